// Round 1
// baseline (190.376 us; speedup 1.0000x reference)
//
#include <hip/hip_runtime.h>

// ChunkRanker: out[n] = realism(std(chunk_n)) + 0.15 + 0.2*cosine(chunk_n[0:10,:], ctx[-10:,:])
// chunks: [4096, 128, 64] fp32 (134 MB, read exactly once -> memory-bound floor ~20 us).
// R3: one WAVE per chunk (no LDS, no __syncthreads, no block-wide epilogue).
//     Grid 1024 x 256 = 4096 waves, all resident at once (4 blocks/CU, 16 waves/CU):
//     zero block turnover, each CU streams its 524 KB share uninterrupted.
//     Loads double-buffered 8+8 dwordx4 in flight per lane.

#define N_CHUNKS   4096
#define CHUNK_F4   2048         // 128*64/4 float4 per chunk
#define CTX_OFF_F4 1888         // (118*64)/4 — last 10 rows of previous_context

__global__ __launch_bounds__(256, 4) void chunk_ranker_kernel(
    const float* __restrict__ chunks,
    const float* __restrict__ prev_ctx,
    float* __restrict__ out)
{
    const int wave = threadIdx.x >> 6;
    const int lane = threadIdx.x & 63;
    const int n    = (blockIdx.x << 2) + wave;     // one chunk per wave

    const float4* __restrict__ c4   = (const float4*)chunks + (size_t)n * CHUNK_F4;
    const float4* __restrict__ ctx4 = (const float4*)prev_ctx + CTX_OFF_F4;

    // ---- double-buffered streaming: 8+8 dwordx4 in flight per lane ----
    float4 va[8], vb[8];
    #pragma unroll
    for (int j = 0; j < 8; ++j) va[j] = c4[j * 64 + lane];          // f4 idx 0..511
    #pragma unroll
    for (int j = 0; j < 8; ++j) vb[j] = c4[(8 + j) * 64 + lane];    // f4 idx 512..1023

    float sum = 0.f, sumsq = 0.f;
    float dot = 0.f, ssq = 0.f, csq = 0.f;

    // Boundary terms: first 160 float4 = va[0] (all lanes), va[1] (all lanes),
    // va[2] (lanes < 32). ctx is 2.5 KB -> L2-resident after first touch.
    {
        float4 a0 = va[0], a1 = va[1];
        float4 c0 = ctx4[lane];
        float4 c1 = ctx4[64 + lane];
        dot = a0.x*c0.x + a0.y*c0.y + a0.z*c0.z + a0.w*c0.w
            + a1.x*c1.x + a1.y*c1.y + a1.z*c1.z + a1.w*c1.w;
        ssq = a0.x*a0.x + a0.y*a0.y + a0.z*a0.z + a0.w*a0.w
            + a1.x*a1.x + a1.y*a1.y + a1.z*a1.z + a1.w*a1.w;
        csq = c0.x*c0.x + c0.y*c0.y + c0.z*c0.z + c0.w*c0.w
            + c1.x*c1.x + c1.y*c1.y + c1.z*c1.z + c1.w*c1.w;
        if (lane < 32) {
            float4 a2 = va[2];
            float4 c2 = ctx4[128 + lane];
            dot += a2.x*c2.x + a2.y*c2.y + a2.z*c2.z + a2.w*c2.w;
            ssq += a2.x*a2.x + a2.y*a2.y + a2.z*a2.z + a2.w*a2.w;
            csq += c2.x*c2.x + c2.y*c2.y + c2.z*c2.z + c2.w*c2.w;
        }
    }

    // consume va (0..511), refill with f4 idx 1024..1535
    #pragma unroll
    for (int j = 0; j < 8; ++j) {
        float4 v = va[j];
        sum   += (v.x + v.y) + (v.z + v.w);
        sumsq += v.x*v.x + v.y*v.y + v.z*v.z + v.w*v.w;
    }
    #pragma unroll
    for (int j = 0; j < 8; ++j) va[j] = c4[(16 + j) * 64 + lane];

    // consume vb (512..1023), refill with f4 idx 1536..2047
    #pragma unroll
    for (int j = 0; j < 8; ++j) {
        float4 v = vb[j];
        sum   += (v.x + v.y) + (v.z + v.w);
        sumsq += v.x*v.x + v.y*v.y + v.z*v.z + v.w*v.w;
    }
    #pragma unroll
    for (int j = 0; j < 8; ++j) vb[j] = c4[(24 + j) * 64 + lane];

    // consume the last two batches
    #pragma unroll
    for (int j = 0; j < 8; ++j) {
        float4 v = va[j];
        sum   += (v.x + v.y) + (v.z + v.w);
        sumsq += v.x*v.x + v.y*v.y + v.z*v.z + v.w*v.w;
    }
    #pragma unroll
    for (int j = 0; j < 8; ++j) {
        float4 v = vb[j];
        sum   += (v.x + v.y) + (v.z + v.w);
        sumsq += v.x*v.x + v.y*v.y + v.z*v.z + v.w*v.w;
    }

    // ---- wave-64 butterfly reduce (5 values), no LDS, no barrier ----
    #pragma unroll
    for (int off = 32; off > 0; off >>= 1) {
        sum   += __shfl_down(sum, off);
        sumsq += __shfl_down(sumsq, off);
        dot   += __shfl_down(dot, off);
        ssq   += __shfl_down(ssq, off);
        csq   += __shfl_down(csq, off);
    }

    if (lane == 0) {
        const float M = 8192.f;                       // 128*64, ddof=1
        float var = (sumsq - sum * sum / M) / (M - 1.f);
        float sd  = sqrtf(fmaxf(var, 0.f));

        float realism;
        if (sd < 0.01f)      realism = sd * 10.f;
        else if (sd > 0.5f)  realism = 0.5f / sd;
        else                 realism = 1.f - fabsf(sd - 0.1f);

        float denom    = fmaxf(sqrtf(ssq) * sqrtf(csq), 1e-8f);
        float boundary = dot / denom;

        out[n] = realism + 0.3f * 0.5f + 0.2f * boundary;
    }
}

extern "C" void kernel_launch(void* const* d_in, const int* in_sizes, int n_in,
                              void* d_out, int out_size, void* d_ws, size_t ws_size,
                              hipStream_t stream) {
    const float* chunks   = (const float*)d_in[0];   // [4096,128,64]
    // d_in[1] = regime_probs [9] — unused (regime_consistency is constant 0.5)
    const float* prev_ctx = (const float*)d_in[2];   // [128,64]
    float* out = (float*)d_out;                      // [4096]

    chunk_ranker_kernel<<<N_CHUNKS / 4, 256, 0, stream>>>(chunks, prev_ctx, out);
}